// Round 20
// baseline (171.129 us; speedup 1.0000x reference)
//
#include <hip/hip_runtime.h>

#define NN 51681
#define EE 2048
#define Z_OFF (51681LL * 2048LL)

typedef __bf16 bf16x8 __attribute__((ext_vector_type(8)));
typedef unsigned short ushort8 __attribute__((ext_vector_type(8)));
typedef float floatx4 __attribute__((ext_vector_type(4)));

__device__ inline unsigned short f2bf(float x) {
    unsigned u = __float_as_uint(x);
    unsigned r = (u + 0x7FFFu + ((u >> 16) & 1u)) >> 16;   // round-to-nearest-even
    return (unsigned short)r;
}
__device__ inline void nt_store4(float* p, floatx4 v) {
    __builtin_nontemporal_store(v, reinterpret_cast<floatx4*>(p));
}

// -------- fused init: W4 convert (RTN hi-only) + deg init + zero touched E4 rows -----

__global__ void init_k(const float* __restrict__ W4,
                       ushort* __restrict__ wthi,
                       float* __restrict__ deg, const int* __restrict__ dst,
                       float* __restrict__ E4) {
    int b = blockIdx.x, t = threadIdx.x;
    if (b < 512) {
        int i = b * 256 + t;                       // < 131072
        int k = i >> 11, c = i & 2047;
        wthi[c * 64 + k] = f2bf(W4[i]);            // transposed [col][k], RTN
    } else if (b < 714) {
        int i = (b - 512) * 256 + t;
        if (i < NN) deg[i] = 1.0f;                 // self-loop weight
    } else {
        int j = (b - 714) * 256 + t;               // < 32768 = EE rows x 16 float4
        int e = j >> 4, f = j & 15;
        reinterpret_cast<float4*>(&E4[(long long)dst[e] * 64])[f] =
            make_float4(0.f, 0.f, 0.f, 0.f);
    }
}

__global__ void deg_scatter_k(const int* __restrict__ dst, const float* __restrict__ w,
                              float* __restrict__ deg) {
    int e = blockIdx.x * 256 + threadIdx.x;
    if (e < EE) atomicAdd(&deg[dst[e]], w[e]);
}

// ------------- layer-4 edge scatter: E4[dst] += norm * X[src]  (rows pre-zeroed) -----

__global__ void edge_scatter_k(const int* __restrict__ src, const int* __restrict__ dst,
                               const float* __restrict__ ew, const float* __restrict__ deg,
                               const float* __restrict__ X, float* __restrict__ E) {
    int tid = blockIdx.x * 256 + threadIdx.x;
    if (tid >= EE * 16) return;
    int e = tid >> 4;
    int f = (tid & 15) * 4;
    int s = src[e], d = dst[e];
    float n = rsqrtf(deg[s]) * ew[e] * rsqrtf(deg[d]);
    const float4 v = *reinterpret_cast<const float4*>(&X[(long long)s * 64 + f]);
    float* a = &E[(long long)d * 64 + f];
    atomicAdd(a + 0, n * v.x);
    atomicAdd(a + 1, n * v.y);
    atomicAdd(a + 2, n * v.z);
    atomicAdd(a + 3, n * v.w);
}

// ---- fused small GEMM (R16-verbatim): out = relu((X/deg + edge-scan) @ W + b) ----

template<int K, int FOUT>
__global__ __launch_bounds__(256) void gemm_fused_k(
    const float* __restrict__ X,
    const int* __restrict__ src, const int* __restrict__ dst,
    const float* __restrict__ ew, const float* __restrict__ deg,
    const float* __restrict__ W, const float* __restrict__ bias,
    float* __restrict__ out) {
    constexpr int TPN = FOUT / 4;       // threads per node (16 or 8)
    constexpr int NPB = 256 / TPN;      // nodes per block (16 or 32)
    __shared__ float Ws[K * FOUT];
    __shared__ float As[NPB][K + 4];    // +4 pad: ln-stride hits distinct banks
    __shared__ int qidx[EE];
    __shared__ int qcount;
    int tid = threadIdx.x;
    if (tid == 0) qcount = 0;
    for (int i = tid; i < K * FOUT / 4; i += 256)
        reinterpret_cast<float4*>(Ws)[i] = reinterpret_cast<const float4*>(W)[i];
    int node0 = blockIdx.x * NPB;
    for (int i = tid; i < NPB * (K / 4); i += 256) {
        int r = i / (K / 4);
        int kk = (i - r * (K / 4)) * 4;
        int g = node0 + r;
        float4 v = make_float4(0.f, 0.f, 0.f, 0.f);
        if (g < NN) {
            float s = 1.0f / deg[g];
            float4 xv = *reinterpret_cast<const float4*>(&X[(long long)g * K + kk]);
            v = make_float4(xv.x * s, xv.y * s, xv.z * s, xv.w * s);
        }
        *reinterpret_cast<float4*>(&As[r][kk]) = v;
    }
    __syncthreads();
    for (int e = tid; e < EE; e += 256) {
        unsigned r = (unsigned)(dst[e] - node0);
        if (r < (unsigned)NPB) { int s = atomicAdd(&qcount, 1); qidx[s] = e; }
    }
    __syncthreads();
    int nq = qcount;
    for (int qi = 0; qi < nq; ++qi) {
        int e = qidx[qi];
        int s_ = src[e], d_ = dst[e];
        float c = ew[e] * rsqrtf(deg[s_]) * rsqrtf(deg[d_]);
        int r = d_ - node0;
        if (tid < K) As[r][tid] += c * X[(long long)s_ * K + tid];
    }
    __syncthreads();
    int ln = tid / TPN;
    int n4 = (tid - ln * TPN) * 4;
    int g = node0 + ln;
    if (g >= NN) return;
    float4 acc = *reinterpret_cast<const float4*>(&bias[n4]);
    #pragma unroll
    for (int k = 0; k < K; ++k) {
        float a = As[ln][k];
        float4 w = *reinterpret_cast<const float4*>(&Ws[k * FOUT + n4]);
        acc.x = fmaf(a, w.x, acc.x);
        acc.y = fmaf(a, w.y, acc.y);
        acc.z = fmaf(a, w.z, acc.z);
        acc.w = fmaf(a, w.w, acc.w);
    }
    acc.x = fmaxf(acc.x, 0.f); acc.y = fmaxf(acc.y, 0.f);
    acc.z = fmaxf(acc.z, 0.f); acc.w = fmaxf(acc.w, 0.f);
    *reinterpret_cast<float4*>(&out[(long long)g * FOUT + n4]) = acc;
}

// ---------------- big GEMM: out[N,2048] = (E + H/deg)[N,64] @ W[64,2048] + b ----------
// R19 structure; ONE change: grid order swapped (x = row band, y = col slice) so the
// 8 col-slices of the same 128-row band do NOT launch onto 8 different XCDs.
// Consecutive blocks are adjacent row bands -> each output row is written by ~2 XCDs
// instead of 8 (less writeback interleave into the same DRAM pages).

__global__ __launch_bounds__(512, 2) void gemm_big_k(
    const float* __restrict__ E, const float* __restrict__ H,
    const float* __restrict__ deg,
    const ushort* __restrict__ wthi,
    const float* __restrict__ bias, float* __restrict__ out) {
    __shared__ ushort Whi[256 * 64];   // 32 KB; reused as wave-private flush patches
    int tid  = threadIdx.x;
    int lane = tid & 63;
    int wv   = tid >> 6;               // 0..7
    int rl   = lane & 15;
    int kg   = lane >> 4;              // 0..3
    int cbase = blockIdx.y * 256;      // col slice (slow dim now)
    int node  = blockIdx.x * 128 + wv * 16 + rl;   // row band (fast dim now)
    bool valid = node < NN;

    // ---- stage W slice (hi-only, 256 cols) into LDS, slot-XOR swizzled ----
    {
        const ushort8* sh8 = reinterpret_cast<const ushort8*>(wthi + (size_t)cbase * 64);
        #pragma unroll
        for (int i = tid; i < 2048; i += 512) {
            int col = i >> 3, slot = i & 7;
            int d = col * 8 + (slot ^ (col & 7));
            reinterpret_cast<ushort8*>(Whi)[d] = sh8[i];
        }
    }

    // ---- acc init = bias; node fragments hi/lo (all global loads in prologue) ----
    floatx4 acc[16];
    #pragma unroll
    for (int tl = 0; tl < 16; ++tl)
        acc[tl] = *reinterpret_cast<const floatx4*>(&bias[cbase + tl * 16 + kg * 4]);

    bf16x8 nb_hi[2], nb_lo[2];
    {
        float v[2][8];
        if (valid) {
            float dg = deg[node];
            float s = 1.0f / dg;
            const float* h0 = H + (long long)node * 64 + kg * 8;
            #pragma unroll
            for (int f = 0; f < 2; ++f) {
                float4 ha = *reinterpret_cast<const float4*>(h0 + f * 32);
                float4 hb = *reinterpret_cast<const float4*>(h0 + f * 32 + 4);
                v[f][0] = ha.x * s; v[f][1] = ha.y * s; v[f][2] = ha.z * s; v[f][3] = ha.w * s;
                v[f][4] = hb.x * s; v[f][5] = hb.y * s; v[f][6] = hb.z * s; v[f][7] = hb.w * s;
            }
            if (dg != 1.0f) {   // E row valid only for edge-touched nodes
                const float* e0 = E + (long long)node * 64 + kg * 8;
                #pragma unroll
                for (int f = 0; f < 2; ++f) {
                    float4 ea = *reinterpret_cast<const float4*>(e0 + f * 32);
                    float4 eb = *reinterpret_cast<const float4*>(e0 + f * 32 + 4);
                    v[f][0] += ea.x; v[f][1] += ea.y; v[f][2] += ea.z; v[f][3] += ea.w;
                    v[f][4] += eb.x; v[f][5] += eb.y; v[f][6] += eb.z; v[f][7] += eb.w;
                }
            }
        } else {
            #pragma unroll
            for (int f = 0; f < 2; ++f)
                #pragma unroll
                for (int i = 0; i < 8; ++i) v[f][i] = 0.f;
        }
        #pragma unroll
        for (int f = 0; f < 2; ++f) {
            ushort8 h8, l8;
            #pragma unroll
            for (int i = 0; i < 8; ++i) {
                unsigned u = __float_as_uint(v[f][i]) & 0xFFFF0000u;  // hi = truncate
                h8[i] = (unsigned short)(u >> 16);
                l8[i] = f2bf(v[f][i] - __uint_as_float(u));
            }
            nb_hi[f] = __builtin_bit_cast(bf16x8, h8);
            nb_lo[f] = __builtin_bit_cast(bf16x8, l8);
        }
    }

    __syncthreads();

    // ---- compute: 16 tiles, 4 MFMA each (hi-only W x hi/lo node) ----
    #pragma unroll
    for (int tl = 0; tl < 16; ++tl) {
        int col  = tl * 16 + rl;
        int base = col * 64;
        int s0 = (kg ^ (rl & 7)) * 8;          // k slot kg
        int s1 = ((kg + 4) ^ (rl & 7)) * 8;    // k slot kg+4
        bf16x8 wh0 = *reinterpret_cast<const bf16x8*>(&Whi[base + s0]);
        bf16x8 wh1 = *reinterpret_cast<const bf16x8*>(&Whi[base + s1]);
        acc[tl] = __builtin_amdgcn_mfma_f32_16x16x32_bf16(wh0, nb_hi[0], acc[tl], 0, 0, 0);
        acc[tl] = __builtin_amdgcn_mfma_f32_16x16x32_bf16(wh0, nb_lo[0], acc[tl], 0, 0, 0);
        acc[tl] = __builtin_amdgcn_mfma_f32_16x16x32_bf16(wh1, nb_hi[1], acc[tl], 0, 0, 0);
        acc[tl] = __builtin_amdgcn_mfma_f32_16x16x32_bf16(wh1, nb_lo[1], acc[tl], 0, 0, 0);
    }

    __syncthreads();   // W dead; LDS becomes wave-private flush patches

    // ---- flush: wave-private 4KB patch, 4 passes, NO barriers ----
    float* patch = reinterpret_cast<float*>(Whi) + wv * 1024;   // 4 KB per wave
    int rowbase = blockIdx.x * 128 + wv * 16;
    #pragma unroll
    for (int pass = 0; pass < 4; ++pass) {
        int r0 = pass * 4;
        // stage: the 16 lanes whose rl is in [r0, r0+4) write their 16 tiles
        if ((rl >> 2) == pass) {
            int pr = rl & 3;
            #pragma unroll
            for (int tl = 0; tl < 16; ++tl)
                *reinterpret_cast<floatx4*>(&patch[pr * 256 + tl * 16 + kg * 4]) = acc[tl];
        }
        // store: 4 rows x 1KB contiguous (in-order DS pipe: reads see writes)
        #pragma unroll
        for (int pr = 0; pr < 4; ++pr) {
            floatx4 v = *reinterpret_cast<const floatx4*>(&patch[pr * 256 + lane * 4]);
            int gr = rowbase + r0 + pr;
            if (gr < NN)
                nt_store4(&out[(long long)gr * 2048 + cbase + lane * 4], v);
        }
    }
}

// ---------------- launch ----------------

extern "C" void kernel_launch(void* const* d_in, const int* in_sizes, int n_in,
                              void* d_out, int out_size, void* d_ws, size_t ws_size,
                              hipStream_t stream) {
    const int*   edge_index = (const int*)d_in[0];   // [2, EE]
    const int*   src = edge_index;
    const int*   dst = edge_index + EE;
    const float* ew  = (const float*)d_in[1];
    const float* emb = (const float*)d_in[2];        // [NN,32]
    const float* W1  = (const float*)d_in[3];
    const float* b1  = (const float*)d_in[4];
    const float* W2  = (const float*)d_in[5];
    const float* b2  = (const float*)d_in[6];
    const float* W3  = (const float*)d_in[7];
    const float* b3  = (const float*)d_in[8];
    const float* W4  = (const float*)d_in[9];        // [64,2048]
    const float* b4  = (const float*)d_in[10];

    float* out = (float*)d_out;                      // recon_x [NN,2048]
    float* z   = out + Z_OFF;                        // z [NN,32]

    float* ws   = (float*)d_ws;
    float* deg  = ws;                                 // NN floats
    float* E4   = ws + 51712;                         // NN*64 (layer-4 edge accum)
    float* t1   = E4 + 3307584;                       // NN*64 (x1, then h)
    ushort* wthi = (ushort*)(t1 + 3307584);           // 2048*64

    // prep: W4 convert + deg init + zero touched E4 rows (1 launch)
    init_k<<<842, 256, 0, stream>>>(W4, wthi, deg, dst, E4);
    deg_scatter_k<<<(EE + 255) / 256, 256, 0, stream>>>(dst, ew, deg);

    // Layer 1: x1 = relu(Ahat(emb) @ W1 + b1) -> t1   (edge scan fused)
    gemm_fused_k<32, 64><<<(NN + 15) / 16, 256, 0, stream>>>(
        emb, src, dst, ew, deg, W1, b1, t1);

    // Layer 2: z = relu(Ahat(x1) @ W2 + b2) -> d_out z-region
    gemm_fused_k<64, 32><<<(NN + 31) / 32, 256, 0, stream>>>(
        t1, src, dst, ew, deg, W2, b2, z);

    // Layer 3: h = relu(Ahat(z) @ W3 + b3) -> t1
    gemm_fused_k<32, 64><<<(NN + 15) / 16, 256, 0, stream>>>(
        z, src, dst, ew, deg, W3, b3, t1);

    // Layer 4: E4 += edges(h); recon = (E4 + h/deg) @ W4 + b4 -> d_out
    edge_scatter_k<<<(EE * 16 + 255) / 256, 256, 0, stream>>>(src, dst, ew, deg, t1, E4);
    gemm_big_k<<<dim3(404, 8), 512, 0, stream>>>(E4, t1, deg, wthi, b4, out);
}

// Round 21
// 150.437 us; speedup vs baseline: 1.1375x; 1.1375x over previous
//
#include <hip/hip_runtime.h>

#define NN 51681
#define EE 2048
#define Z_OFF (51681LL * 2048LL)

typedef __bf16 bf16x8 __attribute__((ext_vector_type(8)));
typedef unsigned short ushort8 __attribute__((ext_vector_type(8)));
typedef float floatx4 __attribute__((ext_vector_type(4)));

__device__ inline unsigned short f2bf(float x) {
    unsigned u = __float_as_uint(x);
    unsigned r = (u + 0x7FFFu + ((u >> 16) & 1u)) >> 16;   // round-to-nearest-even
    return (unsigned short)r;
}
__device__ inline void nt_store4(float* p, floatx4 v) {
    __builtin_nontemporal_store(v, reinterpret_cast<floatx4*>(p));
}

// -------- fused init: W4 convert (RTN hi-only) + deg init + zero touched E4 rows -----

__global__ void init_k(const float* __restrict__ W4,
                       ushort* __restrict__ wthi,
                       float* __restrict__ deg, const int* __restrict__ dst,
                       float* __restrict__ E4) {
    int b = blockIdx.x, t = threadIdx.x;
    if (b < 512) {
        int i = b * 256 + t;                       // < 131072
        int k = i >> 11, c = i & 2047;
        wthi[c * 64 + k] = f2bf(W4[i]);            // transposed [col][k], RTN
    } else if (b < 714) {
        int i = (b - 512) * 256 + t;
        if (i < NN) deg[i] = 1.0f;                 // self-loop weight
    } else {
        int j = (b - 714) * 256 + t;               // < 32768 = EE rows x 16 float4
        int e = j >> 4, f = j & 15;
        reinterpret_cast<float4*>(&E4[(long long)dst[e] * 64])[f] =
            make_float4(0.f, 0.f, 0.f, 0.f);
    }
}

__global__ void deg_scatter_k(const int* __restrict__ dst, const float* __restrict__ w,
                              float* __restrict__ deg) {
    int e = blockIdx.x * 256 + threadIdx.x;
    if (e < EE) atomicAdd(&deg[dst[e]], w[e]);
}

// ------------- layer-4 edge scatter: E4[dst] += norm * X[src]  (rows pre-zeroed) -----

__global__ void edge_scatter_k(const int* __restrict__ src, const int* __restrict__ dst,
                               const float* __restrict__ ew, const float* __restrict__ deg,
                               const float* __restrict__ X, float* __restrict__ E) {
    int tid = blockIdx.x * 256 + threadIdx.x;
    if (tid >= EE * 16) return;
    int e = tid >> 4;
    int f = (tid & 15) * 4;
    int s = src[e], d = dst[e];
    float n = rsqrtf(deg[s]) * ew[e] * rsqrtf(deg[d]);
    const float4 v = *reinterpret_cast<const float4*>(&X[(long long)s * 64 + f]);
    float* a = &E[(long long)d * 64 + f];
    atomicAdd(a + 0, n * v.x);
    atomicAdd(a + 1, n * v.y);
    atomicAdd(a + 2, n * v.z);
    atomicAdd(a + 3, n * v.w);
}

// ---- fused small GEMM (R16-verbatim): out = relu((X/deg + edge-scan) @ W + b) ----

template<int K, int FOUT>
__global__ __launch_bounds__(256) void gemm_fused_k(
    const float* __restrict__ X,
    const int* __restrict__ src, const int* __restrict__ dst,
    const float* __restrict__ ew, const float* __restrict__ deg,
    const float* __restrict__ W, const float* __restrict__ bias,
    float* __restrict__ out) {
    constexpr int TPN = FOUT / 4;       // threads per node (16 or 8)
    constexpr int NPB = 256 / TPN;      // nodes per block (16 or 32)
    __shared__ float Ws[K * FOUT];
    __shared__ float As[NPB][K + 4];    // +4 pad: ln-stride hits distinct banks
    __shared__ int qidx[EE];
    __shared__ int qcount;
    int tid = threadIdx.x;
    if (tid == 0) qcount = 0;
    for (int i = tid; i < K * FOUT / 4; i += 256)
        reinterpret_cast<float4*>(Ws)[i] = reinterpret_cast<const float4*>(W)[i];
    int node0 = blockIdx.x * NPB;
    for (int i = tid; i < NPB * (K / 4); i += 256) {
        int r = i / (K / 4);
        int kk = (i - r * (K / 4)) * 4;
        int g = node0 + r;
        float4 v = make_float4(0.f, 0.f, 0.f, 0.f);
        if (g < NN) {
            float s = 1.0f / deg[g];
            float4 xv = *reinterpret_cast<const float4*>(&X[(long long)g * K + kk]);
            v = make_float4(xv.x * s, xv.y * s, xv.z * s, xv.w * s);
        }
        *reinterpret_cast<float4*>(&As[r][kk]) = v;
    }
    __syncthreads();
    for (int e = tid; e < EE; e += 256) {
        unsigned r = (unsigned)(dst[e] - node0);
        if (r < (unsigned)NPB) { int s = atomicAdd(&qcount, 1); qidx[s] = e; }
    }
    __syncthreads();
    int nq = qcount;
    for (int qi = 0; qi < nq; ++qi) {
        int e = qidx[qi];
        int s_ = src[e], d_ = dst[e];
        float c = ew[e] * rsqrtf(deg[s_]) * rsqrtf(deg[d_]);
        int r = d_ - node0;
        if (tid < K) As[r][tid] += c * X[(long long)s_ * K + tid];
    }
    __syncthreads();
    int ln = tid / TPN;
    int n4 = (tid - ln * TPN) * 4;
    int g = node0 + ln;
    if (g >= NN) return;
    float4 acc = *reinterpret_cast<const float4*>(&bias[n4]);
    #pragma unroll
    for (int k = 0; k < K; ++k) {
        float a = As[ln][k];
        float4 w = *reinterpret_cast<const float4*>(&Ws[k * FOUT + n4]);
        acc.x = fmaf(a, w.x, acc.x);
        acc.y = fmaf(a, w.y, acc.y);
        acc.z = fmaf(a, w.z, acc.z);
        acc.w = fmaf(a, w.w, acc.w);
    }
    acc.x = fmaxf(acc.x, 0.f); acc.y = fmaxf(acc.y, 0.f);
    acc.z = fmaxf(acc.z, 0.f); acc.w = fmaxf(acc.w, 0.f);
    *reinterpret_cast<float4*>(&out[(long long)g * FOUT + n4]) = acc;
}

// ---------------- big GEMM: out[N,2048] = (E + H/deg)[N,64] @ W[64,2048] + b ----------
// R19-verbatim (best, 150.7 µs): hi-only W in LDS, 16 tiles x 4 MFMA, wave-private
// barrier-free flush with 1KB-contiguous nt stores; grid x = col slice (default
// round-robin XCD placement — measured best of 3 placement schemes).

__global__ __launch_bounds__(512, 2) void gemm_big_k(
    const float* __restrict__ E, const float* __restrict__ H,
    const float* __restrict__ deg,
    const ushort* __restrict__ wthi,
    const float* __restrict__ bias, float* __restrict__ out) {
    __shared__ ushort Whi[256 * 64];   // 32 KB; reused as wave-private flush patches
    int tid  = threadIdx.x;
    int lane = tid & 63;
    int wv   = tid >> 6;               // 0..7
    int rl   = lane & 15;
    int kg   = lane >> 4;              // 0..3
    int cbase = blockIdx.x * 256;
    int node  = blockIdx.y * 128 + wv * 16 + rl;
    bool valid = node < NN;

    // ---- stage W slice (hi-only, 256 cols) into LDS, slot-XOR swizzled ----
    {
        const ushort8* sh8 = reinterpret_cast<const ushort8*>(wthi + (size_t)cbase * 64);
        #pragma unroll
        for (int i = tid; i < 2048; i += 512) {
            int col = i >> 3, slot = i & 7;
            int d = col * 8 + (slot ^ (col & 7));
            reinterpret_cast<ushort8*>(Whi)[d] = sh8[i];
        }
    }

    // ---- acc init = bias; node fragments hi/lo (all global loads in prologue) ----
    floatx4 acc[16];
    #pragma unroll
    for (int tl = 0; tl < 16; ++tl)
        acc[tl] = *reinterpret_cast<const floatx4*>(&bias[cbase + tl * 16 + kg * 4]);

    bf16x8 nb_hi[2], nb_lo[2];
    {
        float v[2][8];
        if (valid) {
            float dg = deg[node];
            float s = 1.0f / dg;
            const float* h0 = H + (long long)node * 64 + kg * 8;
            #pragma unroll
            for (int f = 0; f < 2; ++f) {
                float4 ha = *reinterpret_cast<const float4*>(h0 + f * 32);
                float4 hb = *reinterpret_cast<const float4*>(h0 + f * 32 + 4);
                v[f][0] = ha.x * s; v[f][1] = ha.y * s; v[f][2] = ha.z * s; v[f][3] = ha.w * s;
                v[f][4] = hb.x * s; v[f][5] = hb.y * s; v[f][6] = hb.z * s; v[f][7] = hb.w * s;
            }
            if (dg != 1.0f) {   // E row valid only for edge-touched nodes
                const float* e0 = E + (long long)node * 64 + kg * 8;
                #pragma unroll
                for (int f = 0; f < 2; ++f) {
                    float4 ea = *reinterpret_cast<const float4*>(e0 + f * 32);
                    float4 eb = *reinterpret_cast<const float4*>(e0 + f * 32 + 4);
                    v[f][0] += ea.x; v[f][1] += ea.y; v[f][2] += ea.z; v[f][3] += ea.w;
                    v[f][4] += eb.x; v[f][5] += eb.y; v[f][6] += eb.z; v[f][7] += eb.w;
                }
            }
        } else {
            #pragma unroll
            for (int f = 0; f < 2; ++f)
                #pragma unroll
                for (int i = 0; i < 8; ++i) v[f][i] = 0.f;
        }
        #pragma unroll
        for (int f = 0; f < 2; ++f) {
            ushort8 h8, l8;
            #pragma unroll
            for (int i = 0; i < 8; ++i) {
                unsigned u = __float_as_uint(v[f][i]) & 0xFFFF0000u;  // hi = truncate
                h8[i] = (unsigned short)(u >> 16);
                l8[i] = f2bf(v[f][i] - __uint_as_float(u));
            }
            nb_hi[f] = __builtin_bit_cast(bf16x8, h8);
            nb_lo[f] = __builtin_bit_cast(bf16x8, l8);
        }
    }

    __syncthreads();

    // ---- compute: 16 tiles, 4 MFMA each (hi-only W x hi/lo node) ----
    #pragma unroll
    for (int tl = 0; tl < 16; ++tl) {
        int col  = tl * 16 + rl;
        int base = col * 64;
        int s0 = (kg ^ (rl & 7)) * 8;          // k slot kg
        int s1 = ((kg + 4) ^ (rl & 7)) * 8;    // k slot kg+4
        bf16x8 wh0 = *reinterpret_cast<const bf16x8*>(&Whi[base + s0]);
        bf16x8 wh1 = *reinterpret_cast<const bf16x8*>(&Whi[base + s1]);
        acc[tl] = __builtin_amdgcn_mfma_f32_16x16x32_bf16(wh0, nb_hi[0], acc[tl], 0, 0, 0);
        acc[tl] = __builtin_amdgcn_mfma_f32_16x16x32_bf16(wh0, nb_lo[0], acc[tl], 0, 0, 0);
        acc[tl] = __builtin_amdgcn_mfma_f32_16x16x32_bf16(wh1, nb_hi[1], acc[tl], 0, 0, 0);
        acc[tl] = __builtin_amdgcn_mfma_f32_16x16x32_bf16(wh1, nb_lo[1], acc[tl], 0, 0, 0);
    }

    __syncthreads();   // W dead; LDS becomes wave-private flush patches

    // ---- flush: wave-private 4KB patch, 4 passes, NO barriers ----
    float* patch = reinterpret_cast<float*>(Whi) + wv * 1024;   // 4 KB per wave
    int rowbase = blockIdx.y * 128 + wv * 16;
    #pragma unroll
    for (int pass = 0; pass < 4; ++pass) {
        int r0 = pass * 4;
        // stage: the 16 lanes whose rl is in [r0, r0+4) write their 16 tiles
        if ((rl >> 2) == pass) {
            int pr = rl & 3;
            #pragma unroll
            for (int tl = 0; tl < 16; ++tl)
                *reinterpret_cast<floatx4*>(&patch[pr * 256 + tl * 16 + kg * 4]) = acc[tl];
        }
        // store: 4 rows x 1KB contiguous (in-order DS pipe: reads see writes)
        #pragma unroll
        for (int pr = 0; pr < 4; ++pr) {
            floatx4 v = *reinterpret_cast<const floatx4*>(&patch[pr * 256 + lane * 4]);
            int gr = rowbase + r0 + pr;
            if (gr < NN)
                nt_store4(&out[(long long)gr * 2048 + cbase + lane * 4], v);
        }
    }
}

// ---------------- launch ----------------

extern "C" void kernel_launch(void* const* d_in, const int* in_sizes, int n_in,
                              void* d_out, int out_size, void* d_ws, size_t ws_size,
                              hipStream_t stream) {
    const int*   edge_index = (const int*)d_in[0];   // [2, EE]
    const int*   src = edge_index;
    const int*   dst = edge_index + EE;
    const float* ew  = (const float*)d_in[1];
    const float* emb = (const float*)d_in[2];        // [NN,32]
    const float* W1  = (const float*)d_in[3];
    const float* b1  = (const float*)d_in[4];
    const float* W2  = (const float*)d_in[5];
    const float* b2  = (const float*)d_in[6];
    const float* W3  = (const float*)d_in[7];
    const float* b3  = (const float*)d_in[8];
    const float* W4  = (const float*)d_in[9];        // [64,2048]
    const float* b4  = (const float*)d_in[10];

    float* out = (float*)d_out;                      // recon_x [NN,2048]
    float* z   = out + Z_OFF;                        // z [NN,32]

    float* ws   = (float*)d_ws;
    float* deg  = ws;                                 // NN floats
    float* E4   = ws + 51712;                         // NN*64 (layer-4 edge accum)
    float* t1   = E4 + 3307584;                       // NN*64 (x1, then h)
    ushort* wthi = (ushort*)(t1 + 3307584);           // 2048*64

    // prep: W4 convert + deg init + zero touched E4 rows (1 launch)
    init_k<<<842, 256, 0, stream>>>(W4, wthi, deg, dst, E4);
    deg_scatter_k<<<(EE + 255) / 256, 256, 0, stream>>>(dst, ew, deg);

    // Layer 1: x1 = relu(Ahat(emb) @ W1 + b1) -> t1   (edge scan fused)
    gemm_fused_k<32, 64><<<(NN + 15) / 16, 256, 0, stream>>>(
        emb, src, dst, ew, deg, W1, b1, t1);

    // Layer 2: z = relu(Ahat(x1) @ W2 + b2) -> d_out z-region
    gemm_fused_k<64, 32><<<(NN + 31) / 32, 256, 0, stream>>>(
        t1, src, dst, ew, deg, W2, b2, z);

    // Layer 3: h = relu(Ahat(z) @ W3 + b3) -> t1
    gemm_fused_k<32, 64><<<(NN + 15) / 16, 256, 0, stream>>>(
        z, src, dst, ew, deg, W3, b3, t1);

    // Layer 4: E4 += edges(h); recon = (E4 + h/deg) @ W4 + b4 -> d_out
    edge_scatter_k<<<(EE * 16 + 255) / 256, 256, 0, stream>>>(src, dst, ew, deg, t1, E4);
    gemm_big_k<<<dim3(8, 404), 512, 0, stream>>>(E4, t1, deg, wthi, b4, out);
}